// Round 6
// baseline (2299.910 us; speedup 1.0000x reference)
//
#include <hip/hip_runtime.h>

#define TT 256

__device__ __forceinline__ float sig_(float x) { return 1.0f / (1.0f + __expf(-x)); }
__device__ __forceinline__ float th_(float x)  { return 1.0f - 2.0f / (__expf(2.0f * x) + 1.0f); }
// wave-uniform scalar from lane (compile-time lane after unroll -> v_readlane imm)
__device__ __forceinline__ float rlf(float v, int lane) {
  return __int_as_float(__builtin_amdgcn_readlane(__float_as_int(v), lane));
}

// ---------------- Layer 0: x[B,T,4] -> h1 sequence in ws ([t][Bc][64]) ---------
// 4 waves, wave w owns K-slice [16w,16w+16) of Whh in VGPRs (64 floats/lane).
// h delivery: 1 ds_read_b64/lane/step (lane 8m+b holds h[b][kb+2m..+1]),
// then v_readlane -> SGPR feeds v_fmac directly. No LDS broadcasts.
// Rule #20: never runtime-index register arrays (acc/w4 indices all unrolled).
// R4 bug fixed: hbuf row must hold all 64 hu columns (+pad), was 34 -> OOB.
__global__ __launch_bounds__(256, 2) void lstm_l0(
    const float* __restrict__ x, const float* __restrict__ Wih,
    const float* __restrict__ Whh, const float* __restrict__ bih,
    const float* __restrict__ bhh, float* __restrict__ h1ws, int Bc)
{
  __shared__ float  hbuf[2][8][68];    // [buf][b][hu 0..63 +pad] h_prev exchange
  __shared__ float4 pbuf[4][64][8];    // [wave][hu][slot b^(hu&7)] partial gates
  const int tid = threadIdx.x;
  const int w = tid >> 6, hu = tid & 63;
  const int wb = blockIdx.x * 8;
  const int kb = w * 16;
  const int b0 = 2 * w;
  const int lb = tid & 7;              // lane's h-slice batch
  const int lm = (tid & 63) >> 3;      // lane's k-pair group 0..7

  float4 w4[4][4];                     // w4[j][g] = Whh[g*64+hu][kb+4j..+3]
#pragma unroll
  for (int j = 0; j < 4; ++j)
#pragma unroll
    for (int g = 0; g < 4; ++g)
      w4[j][g] = *(const float4*)(Whh + (size_t)(g * 64 + hu) * 64 + kb + 4 * j);
  float4 wih[4];
  float cb[4];
#pragma unroll
  for (int g = 0; g < 4; ++g) {
    wih[g] = *(const float4*)(Wih + (size_t)(g * 64 + hu) * 4);
    cb[g] = bih[g * 64 + hu] + bhh[g * 64 + hu];
  }
  for (int i = tid; i < 8 * 68; i += 256) hbuf[0][i / 68][i % 68] = 0.f;

  float creg[2] = {0.f, 0.f};
  float4 xf[2];
#pragma unroll
  for (int i = 0; i < 2; ++i)
    xf[i] = *(const float4*)(x + (size_t)(wb + b0 + i) * TT * 4);
  __syncthreads();

  for (int t = 0; t < TT; ++t) {
    const int cur = t & 1, nxt = cur ^ 1;
    const int t1 = (t + 1 < TT) ? t + 1 : t;
    // per-lane h slice (written by phase C of t-1, after loop-end barrier)
    const float2 hs = *(const float2*)&hbuf[cur][lb][kb + 2 * lm];
    float4 xn[2];
#pragma unroll
    for (int i = 0; i < 2; ++i)
      xn[i] = *(const float4*)(x + ((size_t)(wb + b0 + i) * TT + t1) * 4);

    // phase A: partial gates; h via readlane->SGPR (k_local = 4j+r at lane 8m+b)
    float acc[8][4];
#pragma unroll
    for (int b = 0; b < 8; ++b)
#pragma unroll
      for (int g = 0; g < 4; ++g) acc[b][g] = 0.f;
#pragma unroll
    for (int j = 0; j < 4; ++j) {
#pragma unroll
      for (int b = 0; b < 8; ++b) {
        const int ln0 = 8 * (2 * j) + b, ln1 = 8 * (2 * j + 1) + b;
        const float h0 = rlf(hs.x, ln0), h1 = rlf(hs.y, ln0);
        const float h2 = rlf(hs.x, ln1), h3 = rlf(hs.y, ln1);
#pragma unroll
        for (int g = 0; g < 4; ++g)
          acc[b][g] += h0 * w4[j][g].x + h1 * w4[j][g].y +
                       h2 * w4[j][g].z + h3 * w4[j][g].w;
      }
    }
    // phase B: publish partials
#pragma unroll
    for (int b = 0; b < 8; ++b)
      pbuf[w][hu][b ^ (hu & 7)] =
          make_float4(acc[b][0], acc[b][1], acc[b][2], acc[b][3]);
    __syncthreads();
    // phase C: duty batches — partials from LDS only
#pragma unroll
    for (int i = 0; i < 2; ++i) {
      const int b = b0 + i;
      float s0 = cb[0], s1 = cb[1], s2 = cb[2], s3 = cb[3];
      const float4 xv = xf[i];
      s0 += xv.x * wih[0].x + xv.y * wih[0].y + xv.z * wih[0].z + xv.w * wih[0].w;
      s1 += xv.x * wih[1].x + xv.y * wih[1].y + xv.z * wih[1].z + xv.w * wih[1].w;
      s2 += xv.x * wih[2].x + xv.y * wih[2].y + xv.z * wih[2].z + xv.w * wih[2].w;
      s3 += xv.x * wih[3].x + xv.y * wih[3].y + xv.z * wih[3].z + xv.w * wih[3].w;
#pragma unroll
      for (int wp = 0; wp < 4; ++wp) {
        const float4 p = pbuf[wp][hu][b ^ (hu & 7)];
        s0 += p.x; s1 += p.y; s2 += p.z; s3 += p.w;
      }
      const float ii = sig_(s0), ff = sig_(s1), gg = th_(s2), oo = sig_(s3);
      const float c = ff * creg[i] + ii * gg;
      const float h = oo * th_(c);
      creg[i] = c;
      hbuf[nxt][b][hu] = h;
      h1ws[((size_t)t * Bc + wb + b) * 64 + hu] = h;
    }
    xf[0] = xn[0]; xf[1] = xn[1];
    __syncthreads();
  }
}

// ---------------- Layer 1 + FC: K=128 = [h1(64) | h2prev(64)] ------------------
// Waves 0/1: k-slices of the h1 half, fed DIRECTLY from global (prefetched t+1).
// Waves 2/3: k-slices of the h2 half, fed from the tiny LDS h2 exchange.
__global__ __launch_bounds__(256, 2) void lstm_l1fc(
    const float* __restrict__ h1ws, const float* __restrict__ Wih,
    const float* __restrict__ Whh, const float* __restrict__ bih,
    const float* __restrict__ bhh, const float* __restrict__ Wfc,
    const float* __restrict__ bfc, float* __restrict__ out, int Bc)
{
  __shared__ float  h2b[2][8][68];     // [buf][b][hu 0..63 +pad] h2_prev exchange
  __shared__ float4 pbuf[4][64][8];
  const int tid = threadIdx.x;
  const int w = tid >> 6, hu = tid & 63;
  const int wb = blockIdx.x * 8;
  const int b0 = 2 * w;
  const int lb = tid & 7;
  const int lm = (tid & 63) >> 3;
  const int kw = (w & 1) * 32;         // column offset within the 64-wide half
  const bool isH1 = (w < 2);           // wave-uniform

  const float* Wsrc = isH1 ? Wih : Whh;
  float4 w4[8][4];                     // w4[j][g] = Wsrc[g*64+hu][kw+4j..+3]
#pragma unroll
  for (int j = 0; j < 8; ++j)
#pragma unroll
    for (int g = 0; g < 4; ++g)
      w4[j][g] = *(const float4*)(Wsrc + (size_t)(g * 64 + hu) * 64 + kw + 4 * j);
  float cb[4];
#pragma unroll
  for (int g = 0; g < 4; ++g) cb[g] = bih[g * 64 + hu] + bhh[g * 64 + hu];
  const float wfc = Wfc[hu];
  const float bf0 = bfc[0];

  for (int i = tid; i < 8 * 68; i += 256) h2b[0][i / 68][i % 68] = 0.f;

  float creg[2] = {0.f, 0.f}, hlast[2] = {0.f, 0.f};
  float4 hs;
  if (isH1)  // t=0 slice from global: h[b=lb][k = kw + 4*lm .. +3]
    hs = *(const float4*)(h1ws + ((size_t)0 * Bc + wb + lb) * 64 + kw + 4 * lm);
  __syncthreads();

  for (int t = 0; t < TT; ++t) {
    const int cur = t & 1, nxt = cur ^ 1;
    const int t1 = (t + 1 < TT) ? t + 1 : t;
    if (!isH1) hs = *(const float4*)&h2b[cur][lb][kw + 4 * lm];
    float4 hp;
    if (isH1)  // prefetch next step's h1 slice (not recurrent -> fully hidden)
      hp = *(const float4*)(h1ws + ((size_t)t1 * Bc + wb + lb) * 64 + kw + 4 * lm);

    // phase A: partial gates; h[b][kw+4j+r] = readlane(hs[r], 8j+b)
    float acc[8][4];
#pragma unroll
    for (int b = 0; b < 8; ++b)
#pragma unroll
      for (int g = 0; g < 4; ++g) acc[b][g] = 0.f;
#pragma unroll
    for (int j = 0; j < 8; ++j) {
#pragma unroll
      for (int b = 0; b < 8; ++b) {
        const int ln = 8 * j + b;
        const float h0 = rlf(hs.x, ln), h1 = rlf(hs.y, ln);
        const float h2 = rlf(hs.z, ln), h3 = rlf(hs.w, ln);
#pragma unroll
        for (int g = 0; g < 4; ++g)
          acc[b][g] += h0 * w4[j][g].x + h1 * w4[j][g].y +
                       h2 * w4[j][g].z + h3 * w4[j][g].w;
      }
    }
    // phase B: publish partials
#pragma unroll
    for (int b = 0; b < 8; ++b)
      pbuf[w][hu][b ^ (hu & 7)] =
          make_float4(acc[b][0], acc[b][1], acc[b][2], acc[b][3]);
    __syncthreads();
    // phase C: duty batches
#pragma unroll
    for (int i = 0; i < 2; ++i) {
      const int b = b0 + i;
      float s0 = cb[0], s1 = cb[1], s2 = cb[2], s3 = cb[3];
#pragma unroll
      for (int wp = 0; wp < 4; ++wp) {
        const float4 p = pbuf[wp][hu][b ^ (hu & 7)];
        s0 += p.x; s1 += p.y; s2 += p.z; s3 += p.w;
      }
      const float ii = sig_(s0), ff = sig_(s1), gg = th_(s2), oo = sig_(s3);
      const float c = ff * creg[i] + ii * gg;
      const float h = oo * th_(c);
      creg[i] = c; hlast[i] = h;
      h2b[nxt][b][hu] = h;
    }
    if (isH1) hs = hp;
    __syncthreads();
  }
  // FC epilogue: out[b] = sum_hu h2_last[b][hu]*Wfc[hu] + bfc
  float p0 = hlast[0] * wfc, p1 = hlast[1] * wfc;
#pragma unroll
  for (int off = 32; off >= 1; off >>= 1) {
    p0 += __shfl_xor(p0, off, 64);
    p1 += __shfl_xor(p1, off, 64);
  }
  if (hu == 0) {
    out[wb + b0]     = p0 + bf0;
    out[wb + b0 + 1] = p1 + bf0;
  }
}

extern "C" void kernel_launch(void* const* d_in, const int* in_sizes, int n_in,
                              void* d_out, int out_size, void* d_ws, size_t ws_size,
                              hipStream_t stream) {
  const float* x    = (const float*)d_in[0];
  const float* Wih0 = (const float*)d_in[1];
  const float* Whh0 = (const float*)d_in[2];
  const float* bih0 = (const float*)d_in[3];
  const float* bhh0 = (const float*)d_in[4];
  const float* Wih1 = (const float*)d_in[5];
  const float* Whh1 = (const float*)d_in[6];
  const float* bih1 = (const float*)d_in[7];
  const float* bhh1 = (const float*)d_in[8];
  const float* Wfc  = (const float*)d_in[9];
  const float* bfc  = (const float*)d_in[10];
  float* out = (float*)d_out;
  float* ws  = (float*)d_ws;

  const int B = in_sizes[0] / (TT * 4); // 4096
  // chunk batches so h1 ([T][Bc][64] f32) fits in ws
  const size_t perB = (size_t)TT * 64 * sizeof(float);
  int capB = (int)((ws_size / perB) & ~(size_t)7);
  if (capB < 8) capB = 8;
  if (capB > B) capB = B;

  for (int b0 = 0; b0 < B; b0 += capB) {
    const int cbn = (B - b0 < capB) ? (B - b0) : capB;
    dim3 grid(cbn / 8), block(256);
    lstm_l0<<<grid, block, 0, stream>>>(x + (size_t)b0 * TT * 4, Wih0, Whh0,
                                        bih0, bhh0, ws, cbn);
    lstm_l1fc<<<grid, block, 0, stream>>>(ws, Wih1, Whh1, bih1, bhh1, Wfc, bfc,
                                          out + b0, cbn);
  }
}

// Round 7
// 1676.803 us; speedup vs baseline: 1.3716x; 1.3716x over previous
//
#include <hip/hip_runtime.h>

#define TT 256

__device__ __forceinline__ float sig_(float x) { return 1.0f / (1.0f + __expf(-x)); }
__device__ __forceinline__ float th_(float x)  { return 1.0f - 2.0f / (__expf(2.0f * x) + 1.0f); }
// wave-uniform scalar from lane (compile-time lane after unroll -> v_readlane imm)
__device__ __forceinline__ float rlf(float v, int lane) {
  return __int_as_float(__builtin_amdgcn_readlane(__float_as_int(v), lane));
}
// pin a float4 into VGPRs (empty asm, no code emitted; forces residency)
#define KEEP4(v) asm volatile("" : "+v"((v).x), "+v"((v).y), "+v"((v).z), "+v"((v).w))

// ---------------- Layer 0: x[B,T,4] -> h1 sequence in ws ([t][Bc][64]) ---------
// 4 waves, wave w owns K-slice [16w,16w+16) of Whh in VGPRs (64 floats/lane).
// h delivery: 1 ds_read_b64/lane/step (lane 8m+b holds h[b][kb+2m..+1]),
// then v_readlane -> SGPR feeds v_fma directly. No LDS broadcasts.
// Rule #20: never runtime-index register arrays (acc/w4 indices all unrolled).
__global__ __launch_bounds__(256, 2) void lstm_l0(
    const float* __restrict__ x, const float* __restrict__ Wih,
    const float* __restrict__ Whh, const float* __restrict__ bih,
    const float* __restrict__ bhh, float* __restrict__ h1ws, int Bc)
{
  __shared__ float  hbuf[2][8][68];    // [buf][b][hu 0..63 +pad] h_prev exchange
  __shared__ float4 pbuf[4][64][8];    // [wave][hu][slot b^(hu&7)] partial gates
  const int tid = threadIdx.x;
  const int w = tid >> 6, hu = tid & 63;
  const int wb = blockIdx.x * 8;
  const int kb = w * 16;
  const int b0 = 2 * w;
  const int lb = tid & 7;              // lane's h-slice batch
  const int lm = (tid & 63) >> 3;      // lane's k-pair group 0..7

  float4 w4[4][4];                     // w4[j][g] = Whh[g*64+hu][kb+4j..+3]
#pragma unroll
  for (int j = 0; j < 4; ++j)
#pragma unroll
    for (int g = 0; g < 4; ++g)
      w4[j][g] = *(const float4*)(Whh + (size_t)(g * 64 + hu) * 64 + kb + 4 * j);
  float4 wih[4];
  float cb[4];
#pragma unroll
  for (int g = 0; g < 4; ++g) {
    wih[g] = *(const float4*)(Wih + (size_t)(g * 64 + hu) * 4);
    cb[g] = bih[g * 64 + hu] + bhh[g * 64 + hu];
  }
  for (int i = tid; i < 8 * 68; i += 256) hbuf[0][i / 68][i % 68] = 0.f;

  float creg[2] = {0.f, 0.f};
  float4 xf[2];
#pragma unroll
  for (int i = 0; i < 2; ++i)
    xf[i] = *(const float4*)(x + (size_t)(wb + b0 + i) * TT * 4);
  __syncthreads();

  for (int t = 0; t < TT; ++t) {
    // pin weight slice resident across the loop
#pragma unroll
    for (int j = 0; j < 4; ++j)
#pragma unroll
      for (int g = 0; g < 4; ++g) KEEP4(w4[j][g]);

    const int cur = t & 1, nxt = cur ^ 1;
    const int t1 = (t + 1 < TT) ? t + 1 : t;
    // per-lane h slice (written by phase C of t-1, after loop-end barrier)
    const float2 hs = *(const float2*)&hbuf[cur][lb][kb + 2 * lm];
    float4 xn[2];
#pragma unroll
    for (int i = 0; i < 2; ++i)
      xn[i] = *(const float4*)(x + ((size_t)(wb + b0 + i) * TT + t1) * 4);

    // phase A: partial gates; h via readlane->SGPR (k_local = 4j+r at lane 8m+b)
    float acc[8][4];
#pragma unroll
    for (int b = 0; b < 8; ++b)
#pragma unroll
      for (int g = 0; g < 4; ++g) acc[b][g] = 0.f;
#pragma unroll
    for (int j = 0; j < 4; ++j) {
#pragma unroll
      for (int b = 0; b < 8; ++b) {
        const int ln0 = 8 * (2 * j) + b, ln1 = 8 * (2 * j + 1) + b;
        const float h0 = rlf(hs.x, ln0), h1 = rlf(hs.y, ln0);
        const float h2 = rlf(hs.x, ln1), h3 = rlf(hs.y, ln1);
#pragma unroll
        for (int g = 0; g < 4; ++g) {
          acc[b][g] = fmaf(h0, w4[j][g].x, acc[b][g]);
          acc[b][g] = fmaf(h1, w4[j][g].y, acc[b][g]);
          acc[b][g] = fmaf(h2, w4[j][g].z, acc[b][g]);
          acc[b][g] = fmaf(h3, w4[j][g].w, acc[b][g]);
        }
      }
    }
    // phase B: publish partials
#pragma unroll
    for (int b = 0; b < 8; ++b)
      pbuf[w][hu][b ^ (hu & 7)] =
          make_float4(acc[b][0], acc[b][1], acc[b][2], acc[b][3]);
    __syncthreads();
    // phase C: duty batches — partials from LDS only
#pragma unroll
    for (int i = 0; i < 2; ++i) {
      const int b = b0 + i;
      float s0 = cb[0], s1 = cb[1], s2 = cb[2], s3 = cb[3];
      const float4 xv = xf[i];
      s0 = fmaf(xv.x, wih[0].x, s0); s0 = fmaf(xv.y, wih[0].y, s0);
      s0 = fmaf(xv.z, wih[0].z, s0); s0 = fmaf(xv.w, wih[0].w, s0);
      s1 = fmaf(xv.x, wih[1].x, s1); s1 = fmaf(xv.y, wih[1].y, s1);
      s1 = fmaf(xv.z, wih[1].z, s1); s1 = fmaf(xv.w, wih[1].w, s1);
      s2 = fmaf(xv.x, wih[2].x, s2); s2 = fmaf(xv.y, wih[2].y, s2);
      s2 = fmaf(xv.z, wih[2].z, s2); s2 = fmaf(xv.w, wih[2].w, s2);
      s3 = fmaf(xv.x, wih[3].x, s3); s3 = fmaf(xv.y, wih[3].y, s3);
      s3 = fmaf(xv.z, wih[3].z, s3); s3 = fmaf(xv.w, wih[3].w, s3);
#pragma unroll
      for (int wp = 0; wp < 4; ++wp) {
        const float4 p = pbuf[wp][hu][b ^ (hu & 7)];
        s0 += p.x; s1 += p.y; s2 += p.z; s3 += p.w;
      }
      const float ii = sig_(s0), ff = sig_(s1), gg = th_(s2), oo = sig_(s3);
      const float c = ff * creg[i] + ii * gg;
      const float h = oo * th_(c);
      creg[i] = c;
      hbuf[nxt][b][hu] = h;
      h1ws[((size_t)t * Bc + wb + b) * 64 + hu] = h;
    }
    xf[0] = xn[0]; xf[1] = xn[1];
    __syncthreads();
  }
}

// ---------------- Layer 1 + FC: K=128 = [h1(64) | h2prev(64)] ------------------
// Waves 0/1: k-slices of the h1 half, fed DIRECTLY from global (prefetched t+1).
// Waves 2/3: k-slices of the h2 half, fed from the tiny LDS h2 exchange.
__global__ __launch_bounds__(256, 2) void lstm_l1fc(
    const float* __restrict__ h1ws, const float* __restrict__ Wih,
    const float* __restrict__ Whh, const float* __restrict__ bih,
    const float* __restrict__ bhh, const float* __restrict__ Wfc,
    const float* __restrict__ bfc, float* __restrict__ out, int Bc)
{
  __shared__ float  h2b[2][8][68];     // [buf][b][hu 0..63 +pad] h2_prev exchange
  __shared__ float4 pbuf[4][64][8];
  const int tid = threadIdx.x;
  const int w = tid >> 6, hu = tid & 63;
  const int wb = blockIdx.x * 8;
  const int b0 = 2 * w;
  const int lb = tid & 7;
  const int lm = (tid & 63) >> 3;
  const int kw = (w & 1) * 32;         // column offset within the 64-wide half
  const bool isH1 = (w < 2);           // wave-uniform

  const float* Wsrc = isH1 ? Wih : Whh;
  float4 w4[8][4];                     // w4[j][g] = Wsrc[g*64+hu][kw+4j..+3]
#pragma unroll
  for (int j = 0; j < 8; ++j)
#pragma unroll
    for (int g = 0; g < 4; ++g)
      w4[j][g] = *(const float4*)(Wsrc + (size_t)(g * 64 + hu) * 64 + kw + 4 * j);
  float cb[4];
#pragma unroll
  for (int g = 0; g < 4; ++g) cb[g] = bih[g * 64 + hu] + bhh[g * 64 + hu];
  const float wfc = Wfc[hu];
  const float bf0 = bfc[0];

  for (int i = tid; i < 8 * 68; i += 256) h2b[0][i / 68][i % 68] = 0.f;

  float creg[2] = {0.f, 0.f}, hlast[2] = {0.f, 0.f};
  float4 hs;
  if (isH1)  // t=0 slice from global: h[b=lb][k = kw + 4*lm .. +3]
    hs = *(const float4*)(h1ws + ((size_t)0 * Bc + wb + lb) * 64 + kw + 4 * lm);
  __syncthreads();

  for (int t = 0; t < TT; ++t) {
    // pin weight slice resident across the loop
#pragma unroll
    for (int j = 0; j < 8; ++j)
#pragma unroll
      for (int g = 0; g < 4; ++g) KEEP4(w4[j][g]);

    const int cur = t & 1, nxt = cur ^ 1;
    const int t1 = (t + 1 < TT) ? t + 1 : t;
    if (!isH1) hs = *(const float4*)&h2b[cur][lb][kw + 4 * lm];
    float4 hp;
    if (isH1)  // prefetch next step's h1 slice (not recurrent -> fully hidden)
      hp = *(const float4*)(h1ws + ((size_t)t1 * Bc + wb + lb) * 64 + kw + 4 * lm);

    // phase A: partial gates; h[b][kw+4j+r] = readlane(hs[r], 8j+b)
    float acc[8][4];
#pragma unroll
    for (int b = 0; b < 8; ++b)
#pragma unroll
      for (int g = 0; g < 4; ++g) acc[b][g] = 0.f;
#pragma unroll
    for (int j = 0; j < 8; ++j) {
#pragma unroll
      for (int b = 0; b < 8; ++b) {
        const int ln = 8 * j + b;
        const float h0 = rlf(hs.x, ln), h1 = rlf(hs.y, ln);
        const float h2 = rlf(hs.z, ln), h3 = rlf(hs.w, ln);
#pragma unroll
        for (int g = 0; g < 4; ++g) {
          acc[b][g] = fmaf(h0, w4[j][g].x, acc[b][g]);
          acc[b][g] = fmaf(h1, w4[j][g].y, acc[b][g]);
          acc[b][g] = fmaf(h2, w4[j][g].z, acc[b][g]);
          acc[b][g] = fmaf(h3, w4[j][g].w, acc[b][g]);
        }
      }
    }
    // phase B: publish partials
#pragma unroll
    for (int b = 0; b < 8; ++b)
      pbuf[w][hu][b ^ (hu & 7)] =
          make_float4(acc[b][0], acc[b][1], acc[b][2], acc[b][3]);
    __syncthreads();
    // phase C: duty batches
#pragma unroll
    for (int i = 0; i < 2; ++i) {
      const int b = b0 + i;
      float s0 = cb[0], s1 = cb[1], s2 = cb[2], s3 = cb[3];
#pragma unroll
      for (int wp = 0; wp < 4; ++wp) {
        const float4 p = pbuf[wp][hu][b ^ (hu & 7)];
        s0 += p.x; s1 += p.y; s2 += p.z; s3 += p.w;
      }
      const float ii = sig_(s0), ff = sig_(s1), gg = th_(s2), oo = sig_(s3);
      const float c = ff * creg[i] + ii * gg;
      const float h = oo * th_(c);
      creg[i] = c; hlast[i] = h;
      h2b[nxt][b][hu] = h;
    }
    if (isH1) hs = hp;
    __syncthreads();
  }
  // FC epilogue: out[b] = sum_hu h2_last[b][hu]*Wfc[hu] + bfc
  float p0 = hlast[0] * wfc, p1 = hlast[1] * wfc;
#pragma unroll
  for (int off = 32; off >= 1; off >>= 1) {
    p0 += __shfl_xor(p0, off, 64);
    p1 += __shfl_xor(p1, off, 64);
  }
  if (hu == 0) {
    out[wb + b0]     = p0 + bf0;
    out[wb + b0 + 1] = p1 + bf0;
  }
}

extern "C" void kernel_launch(void* const* d_in, const int* in_sizes, int n_in,
                              void* d_out, int out_size, void* d_ws, size_t ws_size,
                              hipStream_t stream) {
  const float* x    = (const float*)d_in[0];
  const float* Wih0 = (const float*)d_in[1];
  const float* Whh0 = (const float*)d_in[2];
  const float* bih0 = (const float*)d_in[3];
  const float* bhh0 = (const float*)d_in[4];
  const float* Wih1 = (const float*)d_in[5];
  const float* Whh1 = (const float*)d_in[6];
  const float* bih1 = (const float*)d_in[7];
  const float* bhh1 = (const float*)d_in[8];
  const float* Wfc  = (const float*)d_in[9];
  const float* bfc  = (const float*)d_in[10];
  float* out = (float*)d_out;
  float* ws  = (float*)d_ws;

  const int B = in_sizes[0] / (TT * 4); // 4096
  // chunk batches so h1 ([T][Bc][64] f32) fits in ws
  const size_t perB = (size_t)TT * 64 * sizeof(float);
  int capB = (int)((ws_size / perB) & ~(size_t)7);
  if (capB < 8) capB = 8;
  if (capB > B) capB = B;

  for (int b0 = 0; b0 < B; b0 += capB) {
    const int cbn = (B - b0 < capB) ? (B - b0) : capB;
    dim3 grid(cbn / 8), block(256);
    lstm_l0<<<grid, block, 0, stream>>>(x + (size_t)b0 * TT * 4, Wih0, Whh0,
                                        bih0, bhh0, ws, cbn);
    lstm_l1fc<<<grid, block, 0, stream>>>(ws, Wih1, Whh1, bih1, bhh1, Wfc, bfc,
                                          out + b0, cbn);
  }
}

// Round 8
// 740.657 us; speedup vs baseline: 3.1052x; 2.2639x over previous
//
#include <hip/hip_runtime.h>
#include <hip/hip_bf16.h>

#define TT 256

typedef __attribute__((ext_vector_type(8))) short bf16x8;
typedef __attribute__((ext_vector_type(4))) float f32x4;
typedef unsigned short us;

#define MFMA(a, b, c) __builtin_amdgcn_mfma_f32_16x16x32_bf16(a, b, c, 0, 0, 0)
#define PIN(v) asm volatile("" : "+v"(v))

__device__ __forceinline__ float sig_(float x) { return 1.0f / (1.0f + __expf(-x)); }
__device__ __forceinline__ float th_(float x)  { return 1.0f - 2.0f / (__expf(2.0f * x) + 1.0f); }

__device__ __forceinline__ void split2(float f, us& hi, us& lo) {
  __hip_bfloat16 h = __float2bfloat16(f);
  __hip_bfloat16 l = __float2bfloat16(f - __bfloat162float(h));
  hi = __builtin_bit_cast(us, h);
  lo = __builtin_bit_cast(us, l);
}
__device__ __forceinline__ void pack8(const float* v, bf16x8& hi, bf16x8& lo) {
#pragma unroll
  for (int e = 0; e < 8; ++e) {
    us h, l; split2(v[e], h, l);
    hi[e] = (short)h; lo[e] = (short)l;
  }
}

// ======================= Layer 0 (MFMA): K=96 = [h(64) | x(4) | pad] ==========
// 8 waves x 16 batches. Wave w: gate rows 32w..32w+31 (2 M-tiles), A-frags in
// VGPRs (bf16 hi/lo). Per step: 18 MFMA, gates exchanged via swizzled gbuf,
// activations VALU, h written to LDS planes (recur) + global planes (for l1).
__global__ __launch_bounds__(512, 2) void lstm_l0(
    const float* __restrict__ x, const float* __restrict__ Wih,
    const float* __restrict__ Whh, const float* __restrict__ bih,
    const float* __restrict__ bhh, us* __restrict__ h1hi, us* __restrict__ h1lo,
    int Bc)
{
  __shared__ us vhi[16][104], vlo[16][104];  // [batch][k 0..95 +pad] bf16 planes
  __shared__ float gbuf[16][264];            // [batch][gate, 4-group XOR-swz]
  const int tid = threadIdx.x;
  const int w = tid >> 6, l = tid & 63;
  const int lr = l & 15, lq = l >> 4;
  const int wb = blockIdx.x * 16;

  // ---- weights -> register A-frags (hi/lo), rows 32w+16mt+lr, k=32kt+8lq+e
  bf16x8 whi[2][3], wlo[2][3];
#pragma unroll
  for (int mt = 0; mt < 2; ++mt) {
    const int row = 32 * w + 16 * mt + lr;
#pragma unroll
    for (int kt = 0; kt < 3; ++kt) {
      float wv[8];
      if (kt < 2) {
        const float4 a = *(const float4*)(Whh + (size_t)row * 64 + 32 * kt + 8 * lq);
        const float4 b = *(const float4*)(Whh + (size_t)row * 64 + 32 * kt + 8 * lq + 4);
        wv[0]=a.x; wv[1]=a.y; wv[2]=a.z; wv[3]=a.w; wv[4]=b.x; wv[5]=b.y; wv[6]=b.z; wv[7]=b.w;
      } else {
#pragma unroll
        for (int e = 0; e < 8; ++e) wv[e] = 0.f;
        if (lq == 0) { // k 64..67 = Wih cols 0..3
          const float4 a = *(const float4*)(Wih + (size_t)row * 4);
          wv[0]=a.x; wv[1]=a.y; wv[2]=a.z; wv[3]=a.w;
        }
      }
      pack8(wv, whi[mt][kt], wlo[mt][kt]);
      PIN(whi[mt][kt]); PIN(wlo[mt][kt]);
    }
  }
  float cb[4];
#pragma unroll
  for (int g = 0; g < 4; ++g) cb[g] = bih[g * 64 + l] + bhh[g * 64 + l];

  for (int i = tid; i < 16 * 104; i += 512) { vhi[i/104][i%104] = 0; vlo[i/104][i%104] = 0; }
  float c0 = 0.f, c1 = 0.f;
  float xpre = 0.f;
  if (tid < 64) xpre = x[((size_t)(wb + (tid >> 2)) * TT) * 4 + (tid & 3)];
  __syncthreads();

  for (int t = 0; t < TT; ++t) {
    const int t1 = (t + 1 < TT) ? t + 1 : t;
    // ---- Phase W: stage x(t) into v planes; prefetch x(t+1)
    if (tid < 64) {
      const int b = tid >> 2, d = tid & 3;
      us hx, lx; split2(xpre, hx, lx);
      vhi[b][64 + d] = hx; vlo[b][64 + d] = lx;
      xpre = x[((size_t)(wb + b) * TT + t1) * 4 + (d)];
    }
    __syncthreads(); // A: v planes complete (h from Act(t-1), x from W(t))
    // ---- Phase M: B-frags + 18 MFMA
    bf16x8 bh[3], bl[3];
#pragma unroll
    for (int kt = 0; kt < 3; ++kt) {
      bh[kt] = *(const bf16x8*)&vhi[lr][32 * kt + 8 * lq];
      bl[kt] = *(const bf16x8*)&vlo[lr][32 * kt + 8 * lq];
    }
    f32x4 acc0 = {0.f, 0.f, 0.f, 0.f}, acc1 = {0.f, 0.f, 0.f, 0.f};
#pragma unroll
    for (int kt = 0; kt < 3; ++kt) {
      acc0 = MFMA(whi[0][kt], bh[kt], acc0); acc1 = MFMA(whi[1][kt], bh[kt], acc1);
      acc0 = MFMA(whi[0][kt], bl[kt], acc0); acc1 = MFMA(whi[1][kt], bl[kt], acc1);
      acc0 = MFMA(wlo[0][kt], bh[kt], acc0); acc1 = MFMA(wlo[1][kt], bh[kt], acc1);
    }
    // ---- Phase E: publish gates (C/D: gate = 32w+16mt+4lq+r, batch = lr)
    {
      const int g40 = (8 * w + lq) ^ (lr & 7);
      *(f32x4*)&gbuf[lr][g40 << 2] = acc0;
      const int g41 = (8 * w + 4 + lq) ^ (lr & 7);
      *(f32x4*)&gbuf[lr][g41 << 2] = acc1;
    }
    __syncthreads(); // B
    // ---- Phase Act: thread owns (hu=l, b=w) and (hu=l, b=w+8)
#pragma unroll
    for (int i = 0; i < 2; ++i) {
      const int b = w + 8 * i;
      float s[4];
#pragma unroll
      for (int g = 0; g < 4; ++g)
        s[g] = gbuf[b][((((16 * g) + (l >> 2)) ^ (b & 7)) << 2) + (l & 3)] + cb[g];
      const float ii = sig_(s[0]), ff = sig_(s[1]), gg = th_(s[2]), oo = sig_(s[3]);
      const float cold = i ? c1 : c0;
      const float c = ff * cold + ii * gg;
      const float h = oo * th_(c);
      if (i) c1 = c; else c0 = c;
      us hh, hl; split2(h, hh, hl);
      vhi[b][l] = hh; vlo[b][l] = hl;
      const size_t gi = ((size_t)t * Bc + wb + b) * 64 + l;
      h1hi[gi] = hh; h1lo[gi] = hl;
    }
    __syncthreads(); // C
  }
}

// ======================= Layer 1 + FC (MFMA): K=128 = [h1 | h2] ===============
__global__ __launch_bounds__(512, 2) void lstm_l1fc(
    const us* __restrict__ h1hi, const us* __restrict__ h1lo,
    const float* __restrict__ Wih, const float* __restrict__ Whh,
    const float* __restrict__ bih, const float* __restrict__ bhh,
    const float* __restrict__ Wfc, const float* __restrict__ bfc,
    float* __restrict__ out, int Bc)
{
  __shared__ us vhi[16][136], vlo[16][136];  // [batch][k 0..127 +pad]
  __shared__ float gbuf[16][264];
  const int tid = threadIdx.x;
  const int w = tid >> 6, l = tid & 63;
  const int lr = l & 15, lq = l >> 4;
  const int wb = blockIdx.x * 16;

  // ---- weights: kt0,1 = Wih1 (h1 half), kt2,3 = Whh1 (h2 half)
  bf16x8 whi[2][4], wlo[2][4];
#pragma unroll
  for (int mt = 0; mt < 2; ++mt) {
    const int row = 32 * w + 16 * mt + lr;
#pragma unroll
    for (int kt = 0; kt < 4; ++kt) {
      const float* src = (kt < 2) ? (Wih + (size_t)row * 64 + 32 * kt + 8 * lq)
                                  : (Whh + (size_t)row * 64 + 32 * (kt - 2) + 8 * lq);
      float wv[8];
      const float4 a = *(const float4*)src;
      const float4 b = *(const float4*)(src + 4);
      wv[0]=a.x; wv[1]=a.y; wv[2]=a.z; wv[3]=a.w; wv[4]=b.x; wv[5]=b.y; wv[6]=b.z; wv[7]=b.w;
      pack8(wv, whi[mt][kt], wlo[mt][kt]);
      PIN(whi[mt][kt]); PIN(wlo[mt][kt]);
    }
  }
  float cb[4];
#pragma unroll
  for (int g = 0; g < 4; ++g) cb[g] = bih[g * 64 + l] + bhh[g * 64 + l];
  const float wfc = Wfc[l];
  const float bf0 = bfc[0];

  for (int i = tid; i < 16 * 72; i += 512) { // zero h2 half (+pad)
    const int r = i / 72, cc = 64 + i % 72;
    vhi[r][cc] = 0; vlo[r][cc] = 0;
  }
  float c0 = 0.f, c1 = 0.f, hlast0 = 0.f, hlast1 = 0.f;
  // h1 staging role: plane pp (0=hi,1=lo), batch pb, k-quad pk4
  const int pp = tid >> 8, pidx = tid & 255, pb = pidx >> 4, pk4 = pidx & 15;
  const us* hsrc = pp ? h1lo : h1hi;
  ushort4 hpre = *(const ushort4*)(hsrc + ((size_t)0 * Bc + wb + pb) * 64 + 4 * pk4);
  __syncthreads();

  for (int t = 0; t < TT; ++t) {
    const int t1 = (t + 1 < TT) ? t + 1 : t;
    // ---- Phase W: stage h1(t); prefetch h1(t+1)
    if (pp) *(ushort4*)&vlo[pb][4 * pk4] = hpre;
    else    *(ushort4*)&vhi[pb][4 * pk4] = hpre;
    hpre = *(const ushort4*)(hsrc + ((size_t)t1 * Bc + wb + pb) * 64 + 4 * pk4);
    __syncthreads(); // A
    // ---- Phase M: B-frags + 24 MFMA
    bf16x8 bh[4], bl[4];
#pragma unroll
    for (int kt = 0; kt < 4; ++kt) {
      bh[kt] = *(const bf16x8*)&vhi[lr][32 * kt + 8 * lq];
      bl[kt] = *(const bf16x8*)&vlo[lr][32 * kt + 8 * lq];
    }
    f32x4 acc0 = {0.f, 0.f, 0.f, 0.f}, acc1 = {0.f, 0.f, 0.f, 0.f};
#pragma unroll
    for (int kt = 0; kt < 4; ++kt) {
      acc0 = MFMA(whi[0][kt], bh[kt], acc0); acc1 = MFMA(whi[1][kt], bh[kt], acc1);
      acc0 = MFMA(whi[0][kt], bl[kt], acc0); acc1 = MFMA(whi[1][kt], bl[kt], acc1);
      acc0 = MFMA(wlo[0][kt], bh[kt], acc0); acc1 = MFMA(wlo[1][kt], bh[kt], acc1);
    }
    // ---- Phase E
    {
      const int g40 = (8 * w + lq) ^ (lr & 7);
      *(f32x4*)&gbuf[lr][g40 << 2] = acc0;
      const int g41 = (8 * w + 4 + lq) ^ (lr & 7);
      *(f32x4*)&gbuf[lr][g41 << 2] = acc1;
    }
    __syncthreads(); // B
    // ---- Phase Act
#pragma unroll
    for (int i = 0; i < 2; ++i) {
      const int b = w + 8 * i;
      float s[4];
#pragma unroll
      for (int g = 0; g < 4; ++g)
        s[g] = gbuf[b][((((16 * g) + (l >> 2)) ^ (b & 7)) << 2) + (l & 3)] + cb[g];
      const float ii = sig_(s[0]), ff = sig_(s[1]), gg = th_(s[2]), oo = sig_(s[3]);
      const float cold = i ? c1 : c0;
      const float c = ff * cold + ii * gg;
      const float h = oo * th_(c);
      if (i) { c1 = c; hlast1 = h; } else { c0 = c; hlast0 = h; }
      us hh, hl; split2(h, hh, hl);
      vhi[b][64 + l] = hh; vlo[b][64 + l] = hl;
    }
    __syncthreads(); // C
  }
  // ---- FC: out[b] = sum_hu h2last[b][hu]*Wfc[hu] + bfc
  float p0 = hlast0 * wfc, p1 = hlast1 * wfc;
#pragma unroll
  for (int off = 32; off >= 1; off >>= 1) {
    p0 += __shfl_xor(p0, off, 64);
    p1 += __shfl_xor(p1, off, 64);
  }
  if (l == 0) {
    out[wb + w]     = p0 + bf0;
    out[wb + w + 8] = p1 + bf0;
  }
}

extern "C" void kernel_launch(void* const* d_in, const int* in_sizes, int n_in,
                              void* d_out, int out_size, void* d_ws, size_t ws_size,
                              hipStream_t stream) {
  const float* x    = (const float*)d_in[0];
  const float* Wih0 = (const float*)d_in[1];
  const float* Whh0 = (const float*)d_in[2];
  const float* bih0 = (const float*)d_in[3];
  const float* bhh0 = (const float*)d_in[4];
  const float* Wih1 = (const float*)d_in[5];
  const float* Whh1 = (const float*)d_in[6];
  const float* bih1 = (const float*)d_in[7];
  const float* bhh1 = (const float*)d_in[8];
  const float* Wfc  = (const float*)d_in[9];
  const float* bfc  = (const float*)d_in[10];
  float* out = (float*)d_out;

  const int B = in_sizes[0] / (TT * 4); // 4096
  // h1 planes (hi+lo bf16): TT*Bc*64*2 ushorts each -> 256 B per (batch, t)
  const size_t perB = (size_t)TT * 256;
  int capB = (int)((ws_size / perB) & ~(size_t)15);
  if (capB < 16) capB = 16;
  if (capB > B) capB = B;

  for (int b0 = 0; b0 < B; b0 += capB) {
    const int cbn = (B - b0 < capB) ? (B - b0) : capB;
    us* h1hi = (us*)d_ws;
    us* h1lo = h1hi + (size_t)TT * cbn * 64;
    dim3 grid(cbn / 16), block(512);
    lstm_l0<<<grid, block, 0, stream>>>(x + (size_t)b0 * TT * 4, Wih0, Whh0,
                                        bih0, bhh0, h1hi, h1lo, cbn);
    lstm_l1fc<<<grid, block, 0, stream>>>(h1hi, h1lo, Wih1, Whh1, bih1, bhh1,
                                          Wfc, bfc, out + b0, cbn);
  }
}

// Round 9
// 585.840 us; speedup vs baseline: 3.9258x; 1.2643x over previous
//
#include <hip/hip_runtime.h>
#include <hip/hip_bf16.h>

#define TT 256

typedef __attribute__((ext_vector_type(8))) short bf16x8;
typedef __attribute__((ext_vector_type(4))) float f32x4;
typedef unsigned short us;

#define MFMA(a, b, c) __builtin_amdgcn_mfma_f32_16x16x32_bf16(a, b, c, 0, 0, 0)
#define PIN(v) asm volatile("" : "+v"(v))

__device__ __forceinline__ float sig_(float x) { return 1.0f / (1.0f + __expf(-x)); }
__device__ __forceinline__ float th_(float x)  { return 1.0f - 2.0f / (__expf(2.0f * x) + 1.0f); }

__device__ __forceinline__ void split2(float f, us& hi, us& lo) {
  __hip_bfloat16 h = __float2bfloat16(f);
  __hip_bfloat16 l = __float2bfloat16(f - __bfloat162float(h));
  hi = __builtin_bit_cast(us, h);
  lo = __builtin_bit_cast(us, l);
}
__device__ __forceinline__ void pack8(const float* v, bf16x8& hi, bf16x8& lo) {
#pragma unroll
  for (int e = 0; e < 8; ++e) {
    us h, l; split2(v[e], h, l);
    hi[e] = (short)h; lo[e] = (short)l;
  }
}

// Interleaved row map: tile row r_t (wave w, m-tile mt) -> physical gate row
//   P(r_t) = (r_t&3)*64 + 8w + 4mt + (r_t>>2)
// => C/D element r of lane (lr,lq) = gate r of (hu = 8w+4mt+lq, batch = lr):
//    activations run directly on the accumulator; no gate exchange needed.
// One barrier per step: M2(recurrent) -> Act -> M1(non-recurrent, t+1) -> stage.

// ======================= Layer 0: x[B,T,4] -> h1 planes in ws ==================
__global__ __launch_bounds__(512, 2) void lstm_l0(
    const float* __restrict__ x, const float* __restrict__ Wih,
    const float* __restrict__ Whh, const float* __restrict__ bih,
    const float* __restrict__ bhh, us* __restrict__ h1hi, us* __restrict__ h1lo,
    int Bc)
{
  __shared__ us hh[2][16][72], hl_[2][16][72];  // h planes dbuf [buf][b][hu]
  __shared__ us xh[2][16][40], xl[2][16][40];   // x planes dbuf (cols 0..3 live)
  const int tid = threadIdx.x;
  const int w = tid >> 6, l = tid & 63;
  const int lr = l & 15, lq = l >> 4;
  const int wb = blockIdx.x * 16;
  const int hu0 = 8 * w + lq, hu1 = 8 * w + 4 + lq;

  bf16x8 whh_h[2][2], whh_l[2][2], wx_h[2], wx_l[2];
  f32x4 bias0, bias1;
#pragma unroll
  for (int mt = 0; mt < 2; ++mt) {
    const int P = (lr & 3) * 64 + 8 * w + 4 * mt + (lr >> 2);
#pragma unroll
    for (int kt = 0; kt < 2; ++kt) {
      float wv[8];
      const float4 a = *(const float4*)(Whh + (size_t)P * 64 + 32 * kt + 8 * lq);
      const float4 b = *(const float4*)(Whh + (size_t)P * 64 + 32 * kt + 8 * lq + 4);
      wv[0]=a.x; wv[1]=a.y; wv[2]=a.z; wv[3]=a.w; wv[4]=b.x; wv[5]=b.y; wv[6]=b.z; wv[7]=b.w;
      pack8(wv, whh_h[mt][kt], whh_l[mt][kt]);
      PIN(whh_h[mt][kt]); PIN(whh_l[mt][kt]);
    }
    float wv[8];
#pragma unroll
    for (int e = 0; e < 8; ++e) wv[e] = 0.f;
    if (lq == 0) {
      const float4 a = *(const float4*)(Wih + (size_t)P * 4);
      wv[0]=a.x; wv[1]=a.y; wv[2]=a.z; wv[3]=a.w;
    }
    pack8(wv, wx_h[mt], wx_l[mt]); PIN(wx_h[mt]); PIN(wx_l[mt]);
  }
#pragma unroll
  for (int r = 0; r < 4; ++r) {
    bias0[r] = bih[r * 64 + hu0] + bhh[r * 64 + hu0];
    bias1[r] = bih[r * 64 + hu1] + bhh[r * 64 + hu1];
  }
  for (int i = tid; i < 2 * 16 * 72; i += 512) { ((us*)hh)[i] = 0; ((us*)hl_)[i] = 0; }
  for (int i = tid; i < 2 * 16 * 40; i += 512) { ((us*)xh)[i] = 0; ((us*)xl)[i] = 0; }
  float xpre = 0.f;
  if (tid < 64) {  // x staging role: batch b, dim d
    const int b = tid >> 2, d = tid & 3;
    const float x0 = x[((size_t)(wb + b) * TT + 0) * 4 + d];
    const float x1 = x[((size_t)(wb + b) * TT + 1) * 4 + d];
    us a, bq;
    split2(x0, a, bq); xh[0][b][d] = a; xl[0][b][d] = bq;
    split2(x1, a, bq); xh[1][b][d] = a; xl[1][b][d] = bq;
    xpre = x[((size_t)(wb + b) * TT + 2) * 4 + d];
  }
  __syncthreads();
  // prologue M1x: gacc = bias + Wx·x(0)
  f32x4 gacc0 = bias0, gacc1 = bias1;
  {
    bf16x8 bxh = *(const bf16x8*)&xh[0][lr][8 * lq];
    bf16x8 bxl = *(const bf16x8*)&xl[0][lr][8 * lq];
    gacc0 = MFMA(wx_h[0], bxh, gacc0); gacc1 = MFMA(wx_h[1], bxh, gacc1);
    gacc0 = MFMA(wx_h[0], bxl, gacc0); gacc1 = MFMA(wx_h[1], bxl, gacc1);
    gacc0 = MFMA(wx_l[0], bxh, gacc0); gacc1 = MFMA(wx_l[1], bxh, gacc1);
  }
  __syncthreads();  // all waves done reading xbuf[0] before window 0 rewrites it
  float c0 = 0.f, c1 = 0.f;
  const int pp = tid >> 8, pidx = tid & 255, pb = pidx >> 4, pk4 = pidx & 15;
#pragma unroll 2
  for (int t = 0; t < TT; ++t) {
    const int cur = t & 1, prv = cur ^ 1, nb = (t + 1) & 1;
    // M2: gacc += Whh·h(t-1)
    {
      bf16x8 fh[2], fl[2];
#pragma unroll
      for (int kt = 0; kt < 2; ++kt) {
        fh[kt] = *(const bf16x8*)&hh[prv][lr][32 * kt + 8 * lq];
        fl[kt] = *(const bf16x8*)&hl_[prv][lr][32 * kt + 8 * lq];
      }
#pragma unroll
      for (int kt = 0; kt < 2; ++kt) {
        gacc0 = MFMA(whh_h[0][kt], fh[kt], gacc0); gacc1 = MFMA(whh_h[1][kt], fh[kt], gacc1);
        gacc0 = MFMA(whh_h[0][kt], fl[kt], gacc0); gacc1 = MFMA(whh_h[1][kt], fl[kt], gacc1);
        gacc0 = MFMA(whh_l[0][kt], fh[kt], gacc0); gacc1 = MFMA(whh_l[1][kt], fh[kt], gacc1);
      }
    }
    // Act directly on accumulators (thread owns gates of (hu0,lr) and (hu1,lr))
    {
      const float ii = sig_(gacc0[0]), ff = sig_(gacc0[1]), gg = th_(gacc0[2]), oo = sig_(gacc0[3]);
      c0 = ff * c0 + ii * gg;
      const float hv = oo * th_(c0);
      us a, bq; split2(hv, a, bq);
      hh[cur][lr][hu0] = a; hl_[cur][lr][hu0] = bq;
    }
    {
      const float ii = sig_(gacc1[0]), ff = sig_(gacc1[1]), gg = th_(gacc1[2]), oo = sig_(gacc1[3]);
      c1 = ff * c1 + ii * gg;
      const float hv = oo * th_(c1);
      us a, bq; split2(hv, a, bq);
      hh[cur][lr][hu1] = a; hl_[cur][lr][hu1] = bq;
    }
    // M1x: non-recurrent part of gates(t+1) (independent -> overlaps Act)
    f32x4 n0 = bias0, n1 = bias1;
    {
      bf16x8 bxh = *(const bf16x8*)&xh[nb][lr][8 * lq];
      bf16x8 bxl = *(const bf16x8*)&xl[nb][lr][8 * lq];
      n0 = MFMA(wx_h[0], bxh, n0); n1 = MFMA(wx_h[1], bxh, n1);
      n0 = MFMA(wx_h[0], bxl, n0); n1 = MFMA(wx_h[1], bxl, n1);
      n0 = MFMA(wx_l[0], bxh, n0); n1 = MFMA(wx_l[1], bxh, n1);
    }
    // Wx: stage x(t+2); prefetch x(t+3)
    if (tid < 64) {
      const int b = tid >> 2, d = tid & 3;
      us a, bq; split2(xpre, a, bq);
      xh[cur][b][d] = a; xl[cur][b][d] = bq;
      const int t3 = (t + 3 < TT) ? (t + 3) : (TT - 1);
      xpre = x[((size_t)(wb + b) * TT + t3) * 4 + d];
    }
    // coalesced copy h(t-1) -> global planes (read-only vs this window's writes)
    if (t > 0) {
      const size_t gi = ((size_t)(t - 1) * Bc + wb + pb) * 64 + 4 * pk4;
      if (pp) { *(ushort4*)(h1lo + gi) = *(const ushort4*)&hl_[prv][pb][4 * pk4]; }
      else    { *(ushort4*)(h1hi + gi) = *(const ushort4*)&hh[prv][pb][4 * pk4]; }
    }
    gacc0 = n0; gacc1 = n1;
    __syncthreads();
  }
  { // epilogue: copy h(255)
    const size_t gi = ((size_t)(TT - 1) * Bc + wb + pb) * 64 + 4 * pk4;
    if (pp) { *(ushort4*)(h1lo + gi) = *(const ushort4*)&hl_[1][pb][4 * pk4]; }
    else    { *(ushort4*)(h1hi + gi) = *(const ushort4*)&hh[1][pb][4 * pk4]; }
  }
}

// ======================= Layer 1 + FC: K = [h1(64) | h2(64)] ===================
__global__ __launch_bounds__(512, 2) void lstm_l1fc(
    const us* __restrict__ h1hi, const us* __restrict__ h1lo,
    const float* __restrict__ Wih, const float* __restrict__ Whh,
    const float* __restrict__ bih, const float* __restrict__ bhh,
    const float* __restrict__ Wfc, const float* __restrict__ bfc,
    float* __restrict__ out, int Bc)
{
  __shared__ us ah[2][16][72], al[2][16][72];   // h1 planes dbuf
  __shared__ us bh_[2][16][72], bl_[2][16][72]; // h2 planes dbuf
  __shared__ float fcbuf[8][16];
  const int tid = threadIdx.x;
  const int w = tid >> 6, l = tid & 63;
  const int lr = l & 15, lq = l >> 4;
  const int wb = blockIdx.x * 16;
  const int hu0 = 8 * w + lq, hu1 = 8 * w + 4 + lq;

  bf16x8 w1h[2][2], w1l[2][2], w2h[2][2], w2l[2][2];
  f32x4 bias0, bias1;
#pragma unroll
  for (int mt = 0; mt < 2; ++mt) {
    const int P = (lr & 3) * 64 + 8 * w + 4 * mt + (lr >> 2);
#pragma unroll
    for (int kt = 0; kt < 2; ++kt) {
      float wv[8];
      float4 a = *(const float4*)(Wih + (size_t)P * 64 + 32 * kt + 8 * lq);
      float4 b = *(const float4*)(Wih + (size_t)P * 64 + 32 * kt + 8 * lq + 4);
      wv[0]=a.x; wv[1]=a.y; wv[2]=a.z; wv[3]=a.w; wv[4]=b.x; wv[5]=b.y; wv[6]=b.z; wv[7]=b.w;
      pack8(wv, w1h[mt][kt], w1l[mt][kt]);
      PIN(w1h[mt][kt]); PIN(w1l[mt][kt]);
      a = *(const float4*)(Whh + (size_t)P * 64 + 32 * kt + 8 * lq);
      b = *(const float4*)(Whh + (size_t)P * 64 + 32 * kt + 8 * lq + 4);
      wv[0]=a.x; wv[1]=a.y; wv[2]=a.z; wv[3]=a.w; wv[4]=b.x; wv[5]=b.y; wv[6]=b.z; wv[7]=b.w;
      pack8(wv, w2h[mt][kt], w2l[mt][kt]);
      PIN(w2h[mt][kt]); PIN(w2l[mt][kt]);
    }
  }
#pragma unroll
  for (int r = 0; r < 4; ++r) {
    bias0[r] = bih[r * 64 + hu0] + bhh[r * 64 + hu0];
    bias1[r] = bih[r * 64 + hu1] + bhh[r * 64 + hu1];
  }
  const float wfc0 = Wfc[hu0], wfc1 = Wfc[hu1];
  for (int i = tid; i < 2 * 16 * 72; i += 512) { ((us*)bh_)[i] = 0; ((us*)bl_)[i] = 0; }
  const int pp = tid >> 8, pidx = tid & 255, pb = pidx >> 4, pk4 = pidx & 15;
  const us* gsrc = pp ? h1lo : h1hi;
  {  // stage h1(0) -> buf0, h1(1) -> buf1
    ushort4 v0 = *(const ushort4*)(gsrc + ((size_t)0 * Bc + wb + pb) * 64 + 4 * pk4);
    ushort4 v1 = *(const ushort4*)(gsrc + ((size_t)1 * Bc + wb + pb) * 64 + 4 * pk4);
    if (pp) { *(ushort4*)&al[0][pb][4 * pk4] = v0; *(ushort4*)&al[1][pb][4 * pk4] = v1; }
    else    { *(ushort4*)&ah[0][pb][4 * pk4] = v0; *(ushort4*)&ah[1][pb][4 * pk4] = v1; }
  }
  ushort4 hpre = *(const ushort4*)(gsrc + ((size_t)2 * Bc + wb + pb) * 64 + 4 * pk4);
  __syncthreads();
  // prologue M1: gacc = bias + W1·h1(0)
  f32x4 gacc0 = bias0, gacc1 = bias1;
  {
    bf16x8 fh[2], fl[2];
#pragma unroll
    for (int kt = 0; kt < 2; ++kt) {
      fh[kt] = *(const bf16x8*)&ah[0][lr][32 * kt + 8 * lq];
      fl[kt] = *(const bf16x8*)&al[0][lr][32 * kt + 8 * lq];
    }
#pragma unroll
    for (int kt = 0; kt < 2; ++kt) {
      gacc0 = MFMA(w1h[0][kt], fh[kt], gacc0); gacc1 = MFMA(w1h[1][kt], fh[kt], gacc1);
      gacc0 = MFMA(w1h[0][kt], fl[kt], gacc0); gacc1 = MFMA(w1h[1][kt], fl[kt], gacc1);
      gacc0 = MFMA(w1l[0][kt], fh[kt], gacc0); gacc1 = MFMA(w1l[1][kt], fh[kt], gacc1);
    }
  }
  __syncthreads();  // all waves done reading abuf[0] before window 0 rewrites it
  float c0 = 0.f, c1 = 0.f, hL0 = 0.f, hL1 = 0.f;
#pragma unroll 2
  for (int t = 0; t < TT; ++t) {
    const int cur = t & 1, prv = cur ^ 1, nb = (t + 1) & 1;
    // M2: gacc += W2·h2(t-1)
    {
      bf16x8 fh[2], fl[2];
#pragma unroll
      for (int kt = 0; kt < 2; ++kt) {
        fh[kt] = *(const bf16x8*)&bh_[prv][lr][32 * kt + 8 * lq];
        fl[kt] = *(const bf16x8*)&bl_[prv][lr][32 * kt + 8 * lq];
      }
#pragma unroll
      for (int kt = 0; kt < 2; ++kt) {
        gacc0 = MFMA(w2h[0][kt], fh[kt], gacc0); gacc1 = MFMA(w2h[1][kt], fh[kt], gacc1);
        gacc0 = MFMA(w2h[0][kt], fl[kt], gacc0); gacc1 = MFMA(w2h[1][kt], fl[kt], gacc1);
        gacc0 = MFMA(w2l[0][kt], fh[kt], gacc0); gacc1 = MFMA(w2l[1][kt], fh[kt], gacc1);
      }
    }
    // Act on accumulators
    {
      const float ii = sig_(gacc0[0]), ff = sig_(gacc0[1]), gg = th_(gacc0[2]), oo = sig_(gacc0[3]);
      c0 = ff * c0 + ii * gg;
      const float hv = oo * th_(c0);
      us a, bq; split2(hv, a, bq);
      bh_[cur][lr][hu0] = a; bl_[cur][lr][hu0] = bq;
      hL0 = hv;
    }
    {
      const float ii = sig_(gacc1[0]), ff = sig_(gacc1[1]), gg = th_(gacc1[2]), oo = sig_(gacc1[3]);
      c1 = ff * c1 + ii * gg;
      const float hv = oo * th_(c1);
      us a, bq; split2(hv, a, bq);
      bh_[cur][lr][hu1] = a; bl_[cur][lr][hu1] = bq;
      hL1 = hv;
    }
    // M1: bias + W1·h1(t+1) (independent -> overlaps Act)
    f32x4 n0 = bias0, n1 = bias1;
    {
      bf16x8 fh[2], fl[2];
#pragma unroll
      for (int kt = 0; kt < 2; ++kt) {
        fh[kt] = *(const bf16x8*)&ah[nb][lr][32 * kt + 8 * lq];
        fl[kt] = *(const bf16x8*)&al[nb][lr][32 * kt + 8 * lq];
      }
#pragma unroll
      for (int kt = 0; kt < 2; ++kt) {
        n0 = MFMA(w1h[0][kt], fh[kt], n0); n1 = MFMA(w1h[1][kt], fh[kt], n1);
        n0 = MFMA(w1h[0][kt], fl[kt], n0); n1 = MFMA(w1h[1][kt], fl[kt], n1);
        n0 = MFMA(w1l[0][kt], fh[kt], n0); n1 = MFMA(w1l[1][kt], fh[kt], n1);
      }
    }
    // W: stage h1(t+2); prefetch h1(t+3)
    if (pp) { *(ushort4*)&al[cur][pb][4 * pk4] = hpre; }
    else    { *(ushort4*)&ah[cur][pb][4 * pk4] = hpre; }
    {
      const int t3 = (t + 3 < TT) ? (t + 3) : (TT - 1);
      hpre = *(const ushort4*)(gsrc + ((size_t)t3 * Bc + wb + pb) * 64 + 4 * pk4);
    }
    gacc0 = n0; gacc1 = n1;
    __syncthreads();
  }
  // FC: out[b=lr] = sum_hu h2last * Wfc + bfc  (reduce over lq, then waves)
  float p = hL0 * wfc0 + hL1 * wfc1;
  p += __shfl_xor(p, 16, 64);
  p += __shfl_xor(p, 32, 64);
  if (l < 16) fcbuf[w][l] = p;
  __syncthreads();
  if (tid < 16) {
    float s = bfc[0];
#pragma unroll
    for (int ww = 0; ww < 8; ++ww) s += fcbuf[ww][tid];
    out[wb + tid] = s;
  }
}

extern "C" void kernel_launch(void* const* d_in, const int* in_sizes, int n_in,
                              void* d_out, int out_size, void* d_ws, size_t ws_size,
                              hipStream_t stream) {
  const float* x    = (const float*)d_in[0];
  const float* Wih0 = (const float*)d_in[1];
  const float* Whh0 = (const float*)d_in[2];
  const float* bih0 = (const float*)d_in[3];
  const float* bhh0 = (const float*)d_in[4];
  const float* Wih1 = (const float*)d_in[5];
  const float* Whh1 = (const float*)d_in[6];
  const float* bih1 = (const float*)d_in[7];
  const float* bhh1 = (const float*)d_in[8];
  const float* Wfc  = (const float*)d_in[9];
  const float* bfc  = (const float*)d_in[10];
  float* out = (float*)d_out;

  const int B = in_sizes[0] / (TT * 4); // 4096
  // h1 planes (hi+lo bf16): 256 B per (batch, t)
  const size_t perB = (size_t)TT * 256;
  int capB = (int)((ws_size / perB) & ~(size_t)15);
  if (capB < 16) capB = 16;
  if (capB > B) capB = B;

  for (int b0 = 0; b0 < B; b0 += capB) {
    const int cbn = (B - b0 < capB) ? (B - b0) : capB;
    us* h1hi = (us*)d_ws;
    us* h1lo = h1hi + (size_t)TT * cbn * 64;
    dim3 grid(cbn / 16), block(512);
    lstm_l0<<<grid, block, 0, stream>>>(x + (size_t)b0 * TT * 4, Wih0, Whh0,
                                        bih0, bhh0, h1hi, h1lo, cbn);
    lstm_l1fc<<<grid, block, 0, stream>>>(h1hi, h1lo, Wih1, Whh1, bih1, bhh1,
                                          Wfc, bfc, out + b0, cbn);
  }
}

// Round 10
// 538.194 us; speedup vs baseline: 4.2734x; 1.0885x over previous
//
#include <hip/hip_runtime.h>
#include <hip/hip_bf16.h>

#define TT 256

typedef __attribute__((ext_vector_type(8))) short bf16x8;
typedef __attribute__((ext_vector_type(4))) float f32x4;
typedef unsigned short us;

#define MFMA(a, b, c) __builtin_amdgcn_mfma_f32_16x16x32_bf16(a, b, c, 0, 0, 0)
#define PIN(v) asm volatile("" : "+v"(v))

__device__ __forceinline__ float sig_(float x) { return 1.0f / (1.0f + __expf(-x)); }
__device__ __forceinline__ float th_(float x)  { return 1.0f - 2.0f / (__expf(2.0f * x) + 1.0f); }

__device__ __forceinline__ void split2(float f, us& hi, us& lo) { // RNE (cold)
  __hip_bfloat16 h = __float2bfloat16(f);
  __hip_bfloat16 l = __float2bfloat16(f - __bfloat162float(h));
  hi = __builtin_bit_cast(us, h);
  lo = __builtin_bit_cast(us, l);
}
__device__ __forceinline__ void tsplit(float f, us& hi, us& lo) { // trunc (hot)
  unsigned u = __float_as_uint(f);
  hi = (us)(u >> 16);
  float hf = __uint_as_float(u & 0xffff0000u);
  lo = (us)(__float_as_uint(f - hf) >> 16);
}
__device__ __forceinline__ void pack8(const float* v, bf16x8& hi, bf16x8& lo) {
#pragma unroll
  for (int e = 0; e < 8; ++e) {
    us h, l; split2(v[e], h, l);
    hi[e] = (short)h; lo[e] = (short)l;
  }
}
__device__ __forceinline__ float actstep(const f32x4 g, float& c) {
  const float ii = sig_(g[0]), ff = sig_(g[1]), gg = th_(g[2]), oo = sig_(g[3]);
  c = ff * c + ii * gg;
  return oo * th_(c);
}

// Fused 2-layer LSTM + FC. 16 batches/block, 8 waves, layer-1 lagged one step:
// step t computes l0(t) and l1(t-1); all LDS reads hit [prv], writes [cur] ->
// ONE barrier/step for both layers. l1's h1-operand IS l0's h-buffer (shared
// fragments). Row map P(r)=(r&3)*64+8w+4mt+(r>>2) puts all 4 gates of
// (hu=8w+4mt+lq, b=lr) into this thread's accumulator -> Act runs in-place.
__global__ __launch_bounds__(512, 2) void lstm_fused(
    const float* __restrict__ x,
    const float* __restrict__ Wih0, const float* __restrict__ Whh0,
    const float* __restrict__ bih0, const float* __restrict__ bhh0,
    const float* __restrict__ Wih1, const float* __restrict__ Whh1,
    const float* __restrict__ bih1, const float* __restrict__ bhh1,
    const float* __restrict__ Wfc, const float* __restrict__ bfc,
    float* __restrict__ out)
{
  __shared__ us h0h[2][16][72], h0l[2][16][72];  // layer0 h planes (dbuf)
  __shared__ us h2h[2][16][72], h2l[2][16][72];  // layer1 h planes (dbuf)
  __shared__ us xh[2][16][40], xl[2][16][40];    // x planes (cols 0..3 live)
  __shared__ float fcbuf[8][16];
  const int tid = threadIdx.x;
  const int w = tid >> 6, l = tid & 63;
  const int lr = l & 15, lq = l >> 4;
  const int wb = blockIdx.x * 16;
  const int hu0 = 8 * w + lq, hu1 = 8 * w + 4 + lq;

  // ---------------- weights -> register fragments (cold) ----------------
  bf16x8 whhh[2][2], whhl[2][2], wxh[2], wxl[2];      // layer0
  bf16x8 w1h[2][2], w1l[2][2], w2h[2][2], w2l[2][2];  // layer1
  f32x4 b0v[2], b1v[2];
#pragma unroll
  for (int mt = 0; mt < 2; ++mt) {
    const int P = (lr & 3) * 64 + 8 * w + 4 * mt + (lr >> 2);
    float wv[8];
#pragma unroll
    for (int kt = 0; kt < 2; ++kt) {
      float4 a = *(const float4*)(Whh0 + (size_t)P * 64 + 32 * kt + 8 * lq);
      float4 b = *(const float4*)(Whh0 + (size_t)P * 64 + 32 * kt + 8 * lq + 4);
      wv[0]=a.x; wv[1]=a.y; wv[2]=a.z; wv[3]=a.w; wv[4]=b.x; wv[5]=b.y; wv[6]=b.z; wv[7]=b.w;
      pack8(wv, whhh[mt][kt], whhl[mt][kt]);
      a = *(const float4*)(Wih1 + (size_t)P * 64 + 32 * kt + 8 * lq);
      b = *(const float4*)(Wih1 + (size_t)P * 64 + 32 * kt + 8 * lq + 4);
      wv[0]=a.x; wv[1]=a.y; wv[2]=a.z; wv[3]=a.w; wv[4]=b.x; wv[5]=b.y; wv[6]=b.z; wv[7]=b.w;
      pack8(wv, w1h[mt][kt], w1l[mt][kt]);
      a = *(const float4*)(Whh1 + (size_t)P * 64 + 32 * kt + 8 * lq);
      b = *(const float4*)(Whh1 + (size_t)P * 64 + 32 * kt + 8 * lq + 4);
      wv[0]=a.x; wv[1]=a.y; wv[2]=a.z; wv[3]=a.w; wv[4]=b.x; wv[5]=b.y; wv[6]=b.z; wv[7]=b.w;
      pack8(wv, w2h[mt][kt], w2l[mt][kt]);
    }
#pragma unroll
    for (int e = 0; e < 8; ++e) wv[e] = 0.f;
    if (lq == 0) {
      const float4 a = *(const float4*)(Wih0 + (size_t)P * 4);
      wv[0]=a.x; wv[1]=a.y; wv[2]=a.z; wv[3]=a.w;
    }
    pack8(wv, wxh[mt], wxl[mt]);
    const int hum = 8 * w + 4 * mt + lq;
#pragma unroll
    for (int r = 0; r < 4; ++r) {
      b0v[mt][r] = bih0[r * 64 + hum] + bhh0[r * 64 + hum];
      b1v[mt][r] = bih1[r * 64 + hum] + bhh1[r * 64 + hum];
    }
  }
  const float wfc0 = Wfc[hu0], wfc1 = Wfc[hu1];

  for (int i = tid; i < 2 * 16 * 72; i += 512) {
    ((us*)h0h)[i] = 0; ((us*)h0l)[i] = 0; ((us*)h2h)[i] = 0; ((us*)h2l)[i] = 0;
  }
  for (int i = tid; i < 2 * 16 * 40; i += 512) { ((us*)xh)[i] = 0; ((us*)xl)[i] = 0; }
  float xpre = 0.f;
  if (tid < 64) {  // stage x(0); prefetch x(1)
    const int b = tid >> 2, d = tid & 3;
    us a, bq; split2(x[((size_t)(wb + b) * TT + 0) * 4 + d], a, bq);
    xh[0][b][d] = a; xl[0][b][d] = bq;
    xpre = x[((size_t)(wb + b) * TT + 1) * 4 + d];
  }
  float c0a = 0.f, c0b = 0.f, c1a = 0.f, c1b = 0.f;
  __syncthreads();

#pragma unroll 2
  for (int t = 0; t < TT; ++t) {
    const int cur = t & 1, prv = cur ^ 1;
#pragma unroll
    for (int mt = 0; mt < 2; ++mt) {  // keep weights pinned across the loop
#pragma unroll
      for (int kt = 0; kt < 2; ++kt) {
        PIN(whhh[mt][kt]); PIN(whhl[mt][kt]);
        PIN(w1h[mt][kt]); PIN(w1l[mt][kt]);
        PIN(w2h[mt][kt]); PIN(w2l[mt][kt]);
      }
      PIN(wxh[mt]); PIN(wxl[mt]);
    }
    // ---- B-fragment reads (all from [prv] / staged x[cur])
    const bf16x8 fxh = *(const bf16x8*)&xh[cur][lr][8 * lq];
    const bf16x8 fxl = *(const bf16x8*)&xl[cur][lr][8 * lq];
    bf16x8 f0h[2], f0l[2], f2h[2], f2l[2];
#pragma unroll
    for (int kt = 0; kt < 2; ++kt) {
      f0h[kt] = *(const bf16x8*)&h0h[prv][lr][32 * kt + 8 * lq];
      f0l[kt] = *(const bf16x8*)&h0l[prv][lr][32 * kt + 8 * lq];
      f2h[kt] = *(const bf16x8*)&h2h[prv][lr][32 * kt + 8 * lq];
      f2l[kt] = *(const bf16x8*)&h2l[prv][lr][32 * kt + 8 * lq];
    }
    // ---- layer0 gates(t) = b0 + Wx·x(t) + Whh·h0(t-1)
    f32x4 gA0 = b0v[0], gA1 = b0v[1];
    gA0 = MFMA(wxh[0], fxh, gA0); gA1 = MFMA(wxh[1], fxh, gA1);
    gA0 = MFMA(wxh[0], fxl, gA0); gA1 = MFMA(wxh[1], fxl, gA1);
    gA0 = MFMA(wxl[0], fxh, gA0); gA1 = MFMA(wxl[1], fxh, gA1);
#pragma unroll
    for (int kt = 0; kt < 2; ++kt) {
      gA0 = MFMA(whhh[0][kt], f0h[kt], gA0); gA1 = MFMA(whhh[1][kt], f0h[kt], gA1);
      gA0 = MFMA(whhh[0][kt], f0l[kt], gA0); gA1 = MFMA(whhh[1][kt], f0l[kt], gA1);
      gA0 = MFMA(whhl[0][kt], f0h[kt], gA0); gA1 = MFMA(whhl[1][kt], f0h[kt], gA1);
    }
    // ---- layer1 gates(t-1) = b1 + W1·h1(t-1) + W2·h2(t-2)  [h1 == h0 planes]
    if (t > 0) {
      f32x4 gB0 = b1v[0], gB1 = b1v[1];
#pragma unroll
      for (int kt = 0; kt < 2; ++kt) {
        gB0 = MFMA(w1h[0][kt], f0h[kt], gB0); gB1 = MFMA(w1h[1][kt], f0h[kt], gB1);
        gB0 = MFMA(w1h[0][kt], f0l[kt], gB0); gB1 = MFMA(w1h[1][kt], f0l[kt], gB1);
        gB0 = MFMA(w1l[0][kt], f0h[kt], gB0); gB1 = MFMA(w1l[1][kt], f0h[kt], gB1);
      }
#pragma unroll
      for (int kt = 0; kt < 2; ++kt) {
        gB0 = MFMA(w2h[0][kt], f2h[kt], gB0); gB1 = MFMA(w2h[1][kt], f2h[kt], gB1);
        gB0 = MFMA(w2h[0][kt], f2l[kt], gB0); gB1 = MFMA(w2h[1][kt], f2l[kt], gB1);
        gB0 = MFMA(w2l[0][kt], f2h[kt], gB0); gB1 = MFMA(w2l[1][kt], f2h[kt], gB1);
      }
      const float h2a = actstep(gB0, c1a);
      const float h2b = actstep(gB1, c1b);
      us a, bq;
      tsplit(h2a, a, bq); h2h[cur][lr][hu0] = a; h2l[cur][lr][hu0] = bq;
      tsplit(h2b, a, bq); h2h[cur][lr][hu1] = a; h2l[cur][lr][hu1] = bq;
    }
    // ---- layer0 Act + h write
    {
      const float h0a = actstep(gA0, c0a);
      const float h0b = actstep(gA1, c0b);
      us a, bq;
      tsplit(h0a, a, bq); h0h[cur][lr][hu0] = a; h0l[cur][lr][hu0] = bq;
      tsplit(h0b, a, bq); h0h[cur][lr][hu1] = a; h0l[cur][lr][hu1] = bq;
    }
    // ---- stage x(t+1); prefetch x(t+2)
    if (tid < 64) {
      const int b = tid >> 2, d = tid & 3;
      us a, bq; tsplit(xpre, a, bq);
      xh[prv][b][d] = a; xl[prv][b][d] = bq;
      const int t2 = (t + 2 < TT) ? t + 2 : TT - 1;
      xpre = x[((size_t)(wb + b) * TT + t2) * 4 + d];
    }
    __syncthreads();
  }
  // ---- epilogue: layer1 step 255 (reads parity 1) + FC
  {
    bf16x8 f0h[2], f0l[2], f2h[2], f2l[2];
#pragma unroll
    for (int kt = 0; kt < 2; ++kt) {
      f0h[kt] = *(const bf16x8*)&h0h[1][lr][32 * kt + 8 * lq];
      f0l[kt] = *(const bf16x8*)&h0l[1][lr][32 * kt + 8 * lq];
      f2h[kt] = *(const bf16x8*)&h2h[1][lr][32 * kt + 8 * lq];
      f2l[kt] = *(const bf16x8*)&h2l[1][lr][32 * kt + 8 * lq];
    }
    f32x4 gB0 = b1v[0], gB1 = b1v[1];
#pragma unroll
    for (int kt = 0; kt < 2; ++kt) {
      gB0 = MFMA(w1h[0][kt], f0h[kt], gB0); gB1 = MFMA(w1h[1][kt], f0h[kt], gB1);
      gB0 = MFMA(w1h[0][kt], f0l[kt], gB0); gB1 = MFMA(w1h[1][kt], f0l[kt], gB1);
      gB0 = MFMA(w1l[0][kt], f0h[kt], gB0); gB1 = MFMA(w1l[1][kt], f0h[kt], gB1);
    }
#pragma unroll
    for (int kt = 0; kt < 2; ++kt) {
      gB0 = MFMA(w2h[0][kt], f2h[kt], gB0); gB1 = MFMA(w2h[1][kt], f2h[kt], gB1);
      gB0 = MFMA(w2h[0][kt], f2l[kt], gB0); gB1 = MFMA(w2h[1][kt], f2l[kt], gB1);
      gB0 = MFMA(w2l[0][kt], f2h[kt], gB0); gB1 = MFMA(w2l[1][kt], f2h[kt], gB1);
    }
    const float hL0 = actstep(gB0, c1a);
    const float hL1 = actstep(gB1, c1b);
    float p = hL0 * wfc0 + hL1 * wfc1;
    p += __shfl_xor(p, 16, 64);
    p += __shfl_xor(p, 32, 64);
    if (l < 16) fcbuf[w][l] = p;
  }
  __syncthreads();
  if (tid < 16) {
    float s = bfc[0];
#pragma unroll
    for (int ww = 0; ww < 8; ++ww) s += fcbuf[ww][tid];
    out[wb + tid] = s;
  }
}

extern "C" void kernel_launch(void* const* d_in, const int* in_sizes, int n_in,
                              void* d_out, int out_size, void* d_ws, size_t ws_size,
                              hipStream_t stream) {
  const float* x    = (const float*)d_in[0];
  const float* Wih0 = (const float*)d_in[1];
  const float* Whh0 = (const float*)d_in[2];
  const float* bih0 = (const float*)d_in[3];
  const float* bhh0 = (const float*)d_in[4];
  const float* Wih1 = (const float*)d_in[5];
  const float* Whh1 = (const float*)d_in[6];
  const float* bih1 = (const float*)d_in[7];
  const float* bhh1 = (const float*)d_in[8];
  const float* Wfc  = (const float*)d_in[9];
  const float* bfc  = (const float*)d_in[10];
  float* out = (float*)d_out;

  const int B = in_sizes[0] / (TT * 4); // 4096
  dim3 grid(B / 16), block(512);
  lstm_fused<<<grid, block, 0, stream>>>(x, Wih0, Whh0, bih0, bhh0, Wih1, Whh1,
                                         bih1, bhh1, Wfc, bfc, out);
}